// Round 1
// baseline (63.892 us; speedup 1.0000x reference)
//
#include <hip/hip_runtime.h>
#include <hip/hip_bf16.h>

#define NB 2
#define NH 16
#define NKVH 4
#define NG 4
#define SEQ 4096
#define DH 64
#define BLK 64
#define NW 8
#define NQB 64
#define LSTR 88  // shorts per LDS row (176 B; 16B-aligned, low bank aliasing)

typedef __attribute__((ext_vector_type(8))) short bf16x8;
typedef __attribute__((ext_vector_type(4))) float f32x4;

__device__ __forceinline__ unsigned short f2bf(float x) {
  union { float f; unsigned u; } a; a.f = x;
  unsigned r = a.u + 0x7fffu + ((a.u >> 16) & 1u);
  return (unsigned short)(r >> 16);
}

__global__ __launch_bounds__(256, 2)
void sattn_kernel(const float* __restrict__ qp, const float* __restrict__ kp,
                  const float* __restrict__ vp, const float* __restrict__ alibi,
                  const int* __restrict__ seg, const int* __restrict__ bidx,
                  float* __restrict__ outp)
{
  const int qb = blockIdx.x, kvh = blockIdx.y, b = blockIdx.z;
  const int tid = threadIdx.x;
  const int wave = tid >> 6, lane = tid & 63;
  const int lr = lane & 15, lg = lane >> 4;

  __shared__ short qlds[NG][BLK][LSTR];   // Q (scaled) bf16, 4 heads
  __shared__ short klds[BLK][LSTR];       // K bf16
  __shared__ short vtlds[DH][LSTR];       // V^T bf16: vtlds[d][n]
  __shared__ short plds[4][16][LSTR];     // per-wave P bf16
  __shared__ int seglds[BLK];

  // ---- stage Q (pre-scaled by 1/sqrt(D)=0.125) for all 4 heads ----
  for (int g = 0; g < NG; ++g) {
    const float4* src = (const float4*)(qp + ((((size_t)b*NH + kvh*NG + g)*SEQ) + (size_t)qb*BLK)*DH);
    #pragma unroll
    for (int it = 0; it < 4; ++it) {
      int i = tid + it*256;
      int row = i >> 4, c4 = i & 15;
      float4 val = src[i];
      ushort4 h;
      h.x = f2bf(val.x * 0.125f); h.y = f2bf(val.y * 0.125f);
      h.z = f2bf(val.z * 0.125f); h.w = f2bf(val.w * 0.125f);
      *(ushort4*)&qlds[g][row][c4*4] = h;
    }
  }

  const int m_glob = qb*BLK + wave*16 + lr;   // this lane's query row (fixed)
  const int sq = seg[b*SEQ + m_glob];
  float slope[NG];
  #pragma unroll
  for (int g = 0; g < NG; ++g) slope[g] = alibi[kvh*NG + g];

  float mrun[NG], lrun[NG];
  f32x4 oacc[NG][4];
  #pragma unroll
  for (int g = 0; g < NG; ++g) {
    mrun[g] = -1e30f; lrun[g] = 0.f;
    #pragma unroll
    for (int dt = 0; dt < 4; ++dt) { f32x4 z = {0.f,0.f,0.f,0.f}; oacc[g][dt] = z; }
  }

  for (int wi = 0; wi < NW; ++wi) {
    const int ki = bidx[qb*NW + wi];
    if (ki < 0) continue;
    __syncthreads();   // previous iteration's LDS reads complete
    // ---- stage K and V^T (bf16) ----
    {
      const size_t kvbase = ((((size_t)b*NKVH + kvh)*SEQ) + (size_t)ki*BLK)*DH;
      const float4* ks = (const float4*)(kp + kvbase);
      const float4* vs = (const float4*)(vp + kvbase);
      #pragma unroll
      for (int it = 0; it < 4; ++it) {
        int i = tid + it*256;
        int row = i >> 4, c4 = i & 15;
        float4 val = ks[i];
        ushort4 h;
        h.x = f2bf(val.x); h.y = f2bf(val.y); h.z = f2bf(val.z); h.w = f2bf(val.w);
        *(ushort4*)&klds[row][c4*4] = h;
        float4 vv = vs[i];
        int d0 = c4*4;
        vtlds[d0+0][row] = (short)f2bf(vv.x);
        vtlds[d0+1][row] = (short)f2bf(vv.y);
        vtlds[d0+2][row] = (short)f2bf(vv.z);
        vtlds[d0+3][row] = (short)f2bf(vv.w);
      }
      if (tid < BLK) seglds[tid] = seg[b*SEQ + ki*BLK + tid];
    }
    __syncthreads();

    int sk[4][4];
    #pragma unroll
    for (int f = 0; f < 4; ++f) {
      int4 t = *(const int4*)&seglds[f*16 + lg*4];
      sk[f][0]=t.x; sk[f][1]=t.y; sk[f][2]=t.z; sk[f][3]=t.w;
    }
    // hoist K (A-op) and V^T (A-op for PV) fragments — shared across the 4 heads
    bf16x8 kf[2][4], vf[2][4];
    #pragma unroll
    for (int s = 0; s < 2; ++s)
      #pragma unroll
      for (int f = 0; f < 4; ++f) {
        kf[s][f] = *(const bf16x8*)&klds[f*16 + lr][s*32 + lg*8];
        vf[s][f] = *(const bf16x8*)&vtlds[f*16 + lr][s*32 + lg*8];
      }

    #pragma unroll
    for (int g = 0; g < NG; ++g) {
      // S^T = K · Q^T : lane holds m = lr (one row), n = f*16 + lg*4 + r
      f32x4 sacc[4];
      #pragma unroll
      for (int f = 0; f < 4; ++f) { f32x4 z = {0.f,0.f,0.f,0.f}; sacc[f] = z; }
      #pragma unroll
      for (int s = 0; s < 2; ++s) {
        bf16x8 qf = *(const bf16x8*)&qlds[g][wave*16 + lr][s*32 + lg*8];
        #pragma unroll
        for (int f = 0; f < 4; ++f)
          sacc[f] = __builtin_amdgcn_mfma_f32_16x16x32_bf16(kf[s][f], qf, sacc[f], 0, 0, 0);
      }
      // ---- mask + ALiBi ----
      float mblk = -1e30f;
      #pragma unroll
      for (int f = 0; f < 4; ++f)
        #pragma unroll
        for (int r = 0; r < 4; ++r) {
          int n_glob = ki*BLK + f*16 + lg*4 + r;
          bool dead = (n_glob > m_glob) || (sk[f][r] != sq);
          float sval = dead ? -1e30f : (sacc[f][r] - slope[g]*(float)(m_glob - n_glob));
          sacc[f][r] = sval;
          mblk = fmaxf(mblk, sval);
        }
      mblk = fmaxf(mblk, __shfl_xor(mblk, 16));
      mblk = fmaxf(mblk, __shfl_xor(mblk, 32));
      const float mnew = fmaxf(mrun[g], mblk);
      const float corr = __expf(mrun[g] - mnew);  // (-1e30)-(-1e30)=0 -> 1, safe
      mrun[g] = mnew;
      float psum = 0.f;
      #pragma unroll
      for (int f = 0; f < 4; ++f)
        #pragma unroll
        for (int rp = 0; rp < 2; ++rp) {
          float p0 = (sacc[f][2*rp]   <= -1e29f) ? 0.f : __expf(sacc[f][2*rp]   - mnew);
          float p1 = (sacc[f][2*rp+1] <= -1e29f) ? 0.f : __expf(sacc[f][2*rp+1] - mnew);
          psum += p0 + p1;
          unsigned pw = (unsigned)f2bf(p0) | ((unsigned)f2bf(p1) << 16);
          *(unsigned*)&plds[wave][lr][f*16 + lg*4 + 2*rp] = pw;
        }
      psum += __shfl_xor(psum, 16);
      psum += __shfl_xor(psum, 32);
      lrun[g] = lrun[g]*corr + psum;
      #pragma unroll
      for (int dt = 0; dt < 4; ++dt) {
        oacc[g][dt][0] *= corr; oacc[g][dt][1] *= corr;
        oacc[g][dt][2] *= corr; oacc[g][dt][3] *= corr;
      }
      // ---- PV: O^T = V^T · P^T ----
      #pragma unroll
      for (int s = 0; s < 2; ++s) {
        bf16x8 pf = *(const bf16x8*)&plds[wave][lr][s*32 + lg*8];
        #pragma unroll
        for (int dt = 0; dt < 4; ++dt)
          oacc[g][dt] = __builtin_amdgcn_mfma_f32_16x16x32_bf16(vf[s][dt], pf, oacc[g][dt], 0, 0, 0);
      }
    }
  }

  // ---- epilogue: normalize + store; lane lr owns row m_glob, d = dt*16 + lg*4 + r ----
  #pragma unroll
  for (int g = 0; g < NG; ++g) {
    float inv = lrun[g] > 0.f ? 1.f/lrun[g] : 0.f;
    float* dst = outp + ((((size_t)b*NH + kvh*NG + g)*SEQ) + (size_t)m_glob)*DH;
    #pragma unroll
    for (int dt = 0; dt < 4; ++dt) {
      float4 o;
      o.x = oacc[g][dt][0]*inv; o.y = oacc[g][dt][1]*inv;
      o.z = oacc[g][dt][2]*inv; o.w = oacc[g][dt][3]*inv;
      *(float4*)&dst[dt*16 + lg*4] = o;
    }
  }
}

extern "C" void kernel_launch(void* const* d_in, const int* in_sizes, int n_in,
                              void* d_out, int out_size, void* d_ws, size_t ws_size,
                              hipStream_t stream) {
  const float* q    = (const float*)d_in[0];
  const float* k    = (const float*)d_in[1];
  const float* v    = (const float*)d_in[2];
  const float* al   = (const float*)d_in[3];
  const int*   seg  = (const int*)d_in[4];
  const int*   bidx = (const int*)d_in[5];
  dim3 grid(NQB, NKVH, NB);
  sattn_kernel<<<grid, 256, 0, stream>>>(q, k, v, al, seg, bidx, (float*)d_out);
}

// Round 2
// 61.529 us; speedup vs baseline: 1.0384x; 1.0384x over previous
//
#include <hip/hip_runtime.h>
#include <hip/hip_bf16.h>

#define NKVH 4
#define SEQ 4096
#define BLK 64
#define NW 8
#define NQB 64
#define KP 72   // K / V^T LDS pitch in shorts (144 B)
#define PP 72   // P LDS pitch in shorts

typedef __attribute__((ext_vector_type(8))) short bf16x8;
typedef __attribute__((ext_vector_type(4))) float f32x4;

// round-half-up f32->bf16 pair pack: result = [bf16(hi) : bf16(lo)]
__device__ __forceinline__ unsigned pkbf(unsigned lo, unsigned hi) {
  return __builtin_amdgcn_perm(hi + 0x8000u, lo + 0x8000u, 0x07060302u);
}

__global__ __launch_bounds__(512, 2)
void sattn_kernel(const float* __restrict__ qp, const float* __restrict__ kp,
                  const float* __restrict__ vp, const float* __restrict__ alibi,
                  const int* __restrict__ seg, const int* __restrict__ bidx,
                  float* __restrict__ outp)
{
  const int qb = blockIdx.x, kvh = blockIdx.y, b = blockIdx.z;
  const int tid = threadIdx.x;
  const int wave = tid >> 6, lane = tid & 63;
  const int lr = lane & 15, lg = lane >> 4;
  const int wr = wave & 3, hp = wave >> 2;   // row-group, head-pair

  __shared__ short klds[2][BLK][KP];
  __shared__ short vtlds[2][BLK][KP];   // [d][n], n chunk-swizzled
  __shared__ short plds[8][16][PP];
  __shared__ int   seglds[2][BLK];

  const int m_glob = qb*BLK + wr*16 + lr;
  const int sq = seg[b*SEQ + m_glob];

  int kis[NW];
  #pragma unroll
  for (int i = 0; i < NW; ++i) kis[i] = bidx[qb*NW + i];

  const float LOG2E = 1.4426950408889634f;
  float nslope[2];
  nslope[0] = -alibi[kvh*4 + hp*2 + 0] * LOG2E;
  nslope[1] = -alibi[kvh*4 + hp*2 + 1] * LOG2E;

  // ---- Q into registers (scaled by 0.125*log2e), bf16 ----
  bf16x8 qf[2][2];
  {
    const float qs = 0.125f * LOG2E;
    #pragma unroll
    for (int hh = 0; hh < 2; ++hh) {
      const float* qrow = qp + ((((size_t)b*16 + kvh*4 + hp*2 + hh)*SEQ) + m_glob)*64;
      #pragma unroll
      for (int s = 0; s < 2; ++s) {
        float4 a = *(const float4*)(qrow + s*32 + lg*8);
        float4 c = *(const float4*)(qrow + s*32 + lg*8 + 4);
        union { unsigned u[4]; bf16x8 v; } cv;
        cv.u[0] = pkbf(__float_as_uint(a.x*qs), __float_as_uint(a.y*qs));
        cv.u[1] = pkbf(__float_as_uint(a.z*qs), __float_as_uint(a.w*qs));
        cv.u[2] = pkbf(__float_as_uint(c.x*qs), __float_as_uint(c.y*qs));
        cv.u[3] = pkbf(__float_as_uint(c.z*qs), __float_as_uint(c.w*qs));
        qf[hh][s] = cv.v;
      }
    }
  }

  float mrun[2] = {-1e30f, -1e30f}, lrun[2] = {0.f, 0.f};
  f32x4 oacc[2][4];
  #pragma unroll
  for (int hh = 0; hh < 2; ++hh)
    #pragma unroll
    for (int dt = 0; dt < 4; ++dt) { f32x4 z = {0.f,0.f,0.f,0.f}; oacc[hh][dt] = z; }

  const size_t kvhead = ((size_t)b*NKVH + kvh)*SEQ;
  uint4 rk0, rk1; unsigned rv[8]; int rs = 0;

  auto ISSUE = [&](int ki) {
    const unsigned* kb = (const unsigned*)(kp + (kvhead + (size_t)ki*BLK)*64);
    rk0 = ((const uint4*)kb)[tid];
    rk1 = ((const uint4*)kb)[tid + 512];
    const unsigned* vb = (const unsigned*)(vp + (kvhead + (size_t)ki*BLK)*64);
    #pragma unroll
    for (int i = 0; i < 8; ++i) rv[i] = vb[(wave*8 + i)*64 + lane];
    rs = (tid < 64) ? seg[b*SEQ + ki*BLK + tid] : 0;
  };

  auto WRITE = [&](int buf) {
    const int row = tid >> 4, c4 = tid & 15;
    uint2 ka, kb2;
    ka.x  = pkbf(rk0.x, rk0.y); ka.y  = pkbf(rk0.z, rk0.w);
    kb2.x = pkbf(rk1.x, rk1.y); kb2.y = pkbf(rk1.z, rk1.w);
    *(uint2*)&klds[buf][row][c4*4]      = ka;
    *(uint2*)&klds[buf][row + 32][c4*4] = kb2;
    uint4 pv;
    pv.x = pkbf(rv[0], rv[1]); pv.y = pkbf(rv[2], rv[3]);
    pv.z = pkbf(rv[4], rv[5]); pv.w = pkbf(rv[6], rv[7]);
    const int cs = wave ^ ((lane >> 3) & 7);           // chunk swizzle along n
    *(uint4*)&vtlds[buf][lane][cs*8] = pv;
    if (tid < 64) seglds[buf][tid] = rs;
  };

  auto COMPUTE = [&](int buf, int ki) {
    int4 skv[4];
    #pragma unroll
    for (int f = 0; f < 4; ++f) skv[f] = *(const int4*)&seglds[buf][f*16 + lg*4];

    bf16x8 kf[2][4], vf[2][4];
    #pragma unroll
    for (int s = 0; s < 2; ++s)
      #pragma unroll
      for (int f = 0; f < 4; ++f) {
        kf[s][f] = *(const bf16x8*)&klds[buf][f*16 + lr][s*32 + lg*8];
        const int d = f*16 + lr;
        vf[s][f] = *(const bf16x8*)&vtlds[buf][d][(((s*4 + lg) ^ ((d >> 3) & 7)) * 8)];
      }

    // g-independent mask/pos precompute: dead -> huge pos_diff
    float pdm[4][4];
    #pragma unroll
    for (int f = 0; f < 4; ++f) {
      const int skr[4] = {skv[f].x, skv[f].y, skv[f].z, skv[f].w};
      #pragma unroll
      for (int r = 0; r < 4; ++r) {
        const int n_glob = ki*BLK + f*16 + lg*4 + r;
        const bool dead = (n_glob > m_glob) || (skr[r] != sq);
        pdm[f][r] = dead ? 3.0e34f : (float)(m_glob - n_glob);
      }
    }

    #pragma unroll
    for (int hh = 0; hh < 2; ++hh) {
      f32x4 sacc[4];
      #pragma unroll
      for (int f = 0; f < 4; ++f) { f32x4 z = {0.f,0.f,0.f,0.f}; sacc[f] = z; }
      #pragma unroll
      for (int s = 0; s < 2; ++s)
        #pragma unroll
        for (int f = 0; f < 4; ++f)
          sacc[f] = __builtin_amdgcn_mfma_f32_16x16x32_bf16(kf[s][f], qf[hh][s], sacc[f], 0, 0, 0);

      float sv[4][4];
      float mblk = -3.0e38f;
      #pragma unroll
      for (int f = 0; f < 4; ++f)
        #pragma unroll
        for (int r = 0; r < 4; ++r) {
          sv[f][r] = fmaf(nslope[hh], pdm[f][r], sacc[f][r]);
          mblk = fmaxf(mblk, sv[f][r]);
        }
      mblk = fmaxf(mblk, __shfl_xor(mblk, 16));
      mblk = fmaxf(mblk, __shfl_xor(mblk, 32));
      const float mnew = fmaxf(mrun[hh], mblk);
      const float corr = __builtin_amdgcn_exp2f(mrun[hh] - mnew);
      mrun[hh] = mnew;

      float psum = 0.f;
      #pragma unroll
      for (int f = 0; f < 4; ++f)
        #pragma unroll
        for (int rp = 0; rp < 2; ++rp) {
          float p0 = __builtin_amdgcn_exp2f(sv[f][2*rp]   - mnew);
          float p1 = __builtin_amdgcn_exp2f(sv[f][2*rp+1] - mnew);
          psum += p0 + p1;
          *(unsigned*)&plds[wave][lr][f*16 + lg*4 + 2*rp] =
              pkbf(__float_as_uint(p0), __float_as_uint(p1));
        }
      psum += __shfl_xor(psum, 16);
      psum += __shfl_xor(psum, 32);
      lrun[hh] = lrun[hh]*corr + psum;
      #pragma unroll
      for (int dt = 0; dt < 4; ++dt) oacc[hh][dt] *= corr;

      #pragma unroll
      for (int s = 0; s < 2; ++s) {
        bf16x8 pf = *(const bf16x8*)&plds[wave][lr][s*32 + lg*8];
        #pragma unroll
        for (int dt = 0; dt < 4; ++dt)
          oacc[hh][dt] = __builtin_amdgcn_mfma_f32_16x16x32_bf16(vf[s][dt], pf, oacc[hh][dt], 0, 0, 0);
      }
    }
  };

  // ---- software-pipelined main loop ----
  ISSUE(kis[0] < 0 ? 0 : kis[0]);
  WRITE(0);
  ISSUE(kis[1] < 0 ? 0 : kis[1]);
  __syncthreads();

  #pragma unroll
  for (int wi = 0; wi < NW; ++wi) {
    const int cur = wi & 1;
    if (wi + 1 < NW) WRITE(cur ^ 1);
    if (wi + 2 < NW) ISSUE(kis[wi+2] < 0 ? 0 : kis[wi+2]);
    if (kis[wi] >= 0) COMPUTE(cur, kis[wi]);
    __syncthreads();
  }

  // ---- epilogue ----
  #pragma unroll
  for (int hh = 0; hh < 2; ++hh) {
    const float inv = lrun[hh] > 0.f ? 1.f/lrun[hh] : 0.f;
    float* dst = outp + ((((size_t)b*16 + kvh*4 + hp*2 + hh)*SEQ) + m_glob)*64;
    #pragma unroll
    for (int dt = 0; dt < 4; ++dt) {
      float4 o;
      o.x = oacc[hh][dt][0]*inv; o.y = oacc[hh][dt][1]*inv;
      o.z = oacc[hh][dt][2]*inv; o.w = oacc[hh][dt][3]*inv;
      *(float4*)&dst[dt*16 + lg*4] = o;
    }
  }
}

extern "C" void kernel_launch(void* const* d_in, const int* in_sizes, int n_in,
                              void* d_out, int out_size, void* d_ws, size_t ws_size,
                              hipStream_t stream) {
  const float* q    = (const float*)d_in[0];
  const float* k    = (const float*)d_in[1];
  const float* v    = (const float*)d_in[2];
  const float* al   = (const float*)d_in[3];
  const int*   sg   = (const int*)d_in[4];
  const int*   bi   = (const int*)d_in[5];
  dim3 grid(NQB, NKVH, 2);
  sattn_kernel<<<grid, 512, 0, stream>>>(q, k, v, al, sg, bi, (float*)d_out);
}